// Round 2
// baseline (137.667 us; speedup 1.0000x reference)
//
#include <hip/hip_runtime.h>
#include <math.h>

#define IMG 512
#define QO  255      // qconv pooled output dim
#define QP  256      // padded row stride of qout
#define C2H 125
#define C2S 128      // padded row stride of c2out
#define C3H 123
#define C3S 128      // padded row stride of c3out

// ---------------------------------------------------------------------------
// build_M: 16 threads, each evolves one column of the 16x16 circuit matrix
// entirely in registers (compile-time gate wiring). No LDS, no syncthreads.
// Mout[row*16+col] includes the (-i)^popcount(col) RX phase fold.
// ---------------------------------------------------------------------------
template<int M_>
__device__ inline void rot_regs(float2* a, float2 U00, float2 U01, float2 U10, float2 U11) {
    #pragma unroll
    for (int s = 0; s < 16; ++s) {
        if (!(s & M_)) {
            float2 a0 = a[s], a1 = a[s | M_];
            a[s]      = make_float2(U00.x*a0.x - U00.y*a0.y + U01.x*a1.x - U01.y*a1.y,
                                    U00.x*a0.y + U00.y*a0.x + U01.x*a1.y + U01.y*a1.x);
            a[s | M_] = make_float2(U10.x*a0.x - U10.y*a0.y + U11.x*a1.x - U11.y*a1.y,
                                    U10.x*a0.y + U10.y*a0.x + U11.x*a1.y + U11.y*a1.x);
        }
    }
}
template<int MC, int MT>
__device__ inline void cnot_regs(float2* a) {
    #pragma unroll
    for (int s = 0; s < 16; ++s) {
        if ((s & MC) && !(s & MT)) {
            float2 t = a[s]; a[s] = a[s | MT]; a[s | MT] = t;
        }
    }
}
__device__ inline void rot_gate_params(float phi, float th, float om,
                                       float2& U00, float2& U01, float2& U10, float2& U11) {
    float ch, sh, ca, sa, cb, sb;
    __sincosf(0.5f * th, &sh, &ch);
    __sincosf(0.5f * (phi + om), &sa, &ca);
    __sincosf(0.5f * (phi - om), &sb, &cb);
    U00 = make_float2( ca*ch, -sa*ch);
    U01 = make_float2(-cb*sh, -sb*sh);
    U10 = make_float2( cb*sh, -sb*sh);
    U11 = make_float2( ca*ch,  sa*ch);
}

__global__ void build_M(const float* __restrict__ qw, float2* __restrict__ Mout) {
    int t = threadIdx.x;
    if (t >= 16) return;
    float2 a[16];
    #pragma unroll
    for (int s = 0; s < 16; ++s) a[s] = make_float2(s == t ? 1.f : 0.f, 0.f);

    float2 U00, U01, U10, U11;
#define ROTG(L, W) rot_gate_params(qw[((L)*4+(W))*3+0], qw[((L)*4+(W))*3+1], qw[((L)*4+(W))*3+2], U00,U01,U10,U11); \
                   rot_regs<(1 << (3-(W)))>(a, U00, U01, U10, U11);
    ROTG(0,0) ROTG(0,1) ROTG(0,2) ROTG(0,3)
    cnot_regs<8,4>(a); cnot_regs<4,2>(a); cnot_regs<2,1>(a); cnot_regs<1,8>(a);
    ROTG(1,0) ROTG(1,1) ROTG(1,2) ROTG(1,3)
    cnot_regs<8,2>(a); cnot_regs<4,1>(a); cnot_regs<2,8>(a); cnot_regs<1,4>(a);
    ROTG(2,0) ROTG(2,1) ROTG(2,2) ROTG(2,3)
    cnot_regs<8,1>(a); cnot_regs<4,8>(a); cnot_regs<2,4>(a); cnot_regs<1,2>(a);
#undef ROTG

    int pc = __popc(t) & 3;
    #pragma unroll
    for (int row = 0; row < 16; ++row) {
        float2 v = a[row], o;
        if      (pc == 0) o = v;
        else if (pc == 1) o = make_float2( v.y, -v.x);   // * (-i)
        else if (pc == 2) o = make_float2(-v.x, -v.y);   // * (-1)
        else              o = make_float2(-v.y,  v.x);   // * (+i)
        Mout[row * 16 + t] = o;
    }
}

// ---------------------------------------------------------------------------
// qconv + sigmoid∘maxpool2. One thread per pooled pixel. M via uniform
// scalar loads (no LDS). out: [4][256(QP) rows? no: ch][i*QP+j], padded.
// ---------------------------------------------------------------------------
__global__ __launch_bounds__(256) void qconv_pool(const float* __restrict__ img,
                                                  const float2* __restrict__ M2,
                                                  float* __restrict__ out) {
    int gid = blockIdx.x * 256 + threadIdx.x;
    if (gid >= QO * QO) return;
    int i = gid / QO, j = gid - i * QO;
    int r0 = 2 * i, c0 = 2 * j;

    float cs[3][3], sn[3][3];
    #pragma unroll
    for (int rr = 0; rr < 3; ++rr)
        #pragma unroll
        for (int cc = 0; cc < 3; ++cc) {
            float v = img[(r0 + rr) * IMG + c0 + cc];
            __sincosf(0.5f * v, &sn[rr][cc], &cs[rr][cc]);
        }

    float mx0 = -1e30f, mx1 = -1e30f, mx2 = -1e30f, mx3 = -1e30f;

    #pragma unroll
    for (int pr = 0; pr < 2; ++pr) {
        #pragma unroll
        for (int pc = 0; pc < 2; ++pc) {
            float c0v = cs[pr][pc],     s0 = sn[pr][pc];
            float c1v = cs[pr][pc+1],   s1 = sn[pr][pc+1];
            float c2v = cs[pr+1][pc],   s2 = sn[pr+1][pc];
            float c3v = cs[pr+1][pc+1], s3 = sn[pr+1][pc+1];
            float t01[4] = {c0v*c1v, c0v*s1, s0*c1v, s0*s1};
            float t23[4] = {c2v*c3v, c2v*s3, s2*c3v, s2*s3};
            float a[16];
            #pragma unroll
            for (int k = 0; k < 16; ++k) a[k] = t01[k >> 2] * t23[k & 3];

            float e0 = 0.f, e1 = 0.f, e2 = 0.f, e3 = 0.f;
            #pragma unroll 4
            for (int rw = 0; rw < 16; ++rw) {
                float re = 0.f, im = 0.f;
                #pragma unroll
                for (int k = 0; k < 16; ++k) {
                    float2 m = M2[rw * 16 + k];   // uniform -> s_load
                    re = fmaf(m.x, a[k], re);
                    im = fmaf(m.y, a[k], im);
                }
                float pp = fmaf(re, re, im * im);
                e0 += (rw & 8) ? -pp : pp;
                e1 += (rw & 4) ? -pp : pp;
                e2 += (rw & 2) ? -pp : pp;
                e3 += (rw & 1) ? -pp : pp;
            }
            mx0 = fmaxf(mx0, e0);
            mx1 = fmaxf(mx1, e1);
            mx2 = fmaxf(mx2, e2);
            mx3 = fmaxf(mx3, e3);
        }
    }

    int o = i * QP + j;
    out[0 * QP * QP + o] = 1.f / (1.f + __expf(-mx0));
    out[1 * QP * QP + o] = 1.f / (1.f + __expf(-mx1));
    out[2 * QP * QP + o] = 1.f / (1.f + __expf(-mx2));
    out[3 * QP * QP + o] = 1.f / (1.f + __expf(-mx3));
}

// ---------------------------------------------------------------------------
// conv2 (4->20, 5x5) + bias + relu + maxpool2. oc = blockIdx.y (uniform
// weights -> scalar loads). in: [4][QP][QP] padded; out: [20][C2H][C2S].
// ---------------------------------------------------------------------------
__global__ __launch_bounds__(256) void conv2_pool(const float* __restrict__ in,
                                                  const float* __restrict__ w,
                                                  const float* __restrict__ b,
                                                  float* __restrict__ out) {
    int oc = blockIdx.y;
    int sp = blockIdx.x * 256 + threadIdx.x;
    if (sp >= C2H * C2H) return;
    int i = sp / C2H, j = sp - i * C2H;
    const float* wb = w + oc * 100;

    float a00 = 0.f, a01 = 0.f, a10 = 0.f, a11 = 0.f;
    #pragma unroll
    for (int ic = 0; ic < 4; ++ic) {
        const float* ip = in + ic * QP * QP + (2 * i) * QP + 2 * j;
        float win[6][6];
        #pragma unroll
        for (int y = 0; y < 6; ++y) {
            #pragma unroll
            for (int h = 0; h < 3; ++h) {
                float2 v = *(const float2*)(ip + y * QP + 2 * h);
                win[y][2*h]   = v.x;
                win[y][2*h+1] = v.y;
            }
        }
        #pragma unroll
        for (int ky = 0; ky < 5; ++ky) {
            #pragma unroll
            for (int kx = 0; kx < 5; ++kx) {
                float wv = wb[ic * 25 + ky * 5 + kx];   // uniform -> s_load
                a00 = fmaf(win[ky][kx],     wv, a00);
                a01 = fmaf(win[ky][kx+1],   wv, a01);
                a10 = fmaf(win[ky+1][kx],   wv, a10);
                a11 = fmaf(win[ky+1][kx+1], wv, a11);
            }
        }
    }
    float m = fmaxf(fmaxf(a00, a01), fmaxf(a10, a11));
    out[oc * C2H * C2S + i * C2S + j] = fmaxf(m + b[oc], 0.f);
}

// ---------------------------------------------------------------------------
// conv3 (20->40, 3x3) + bias + relu. og = blockIdx.y owns 4 output channels
// (uniform weights -> scalar loads). out: [40][C3H][C3S].
// ---------------------------------------------------------------------------
__global__ __launch_bounds__(256) void conv3_k(const float* __restrict__ in,
                                               const float* __restrict__ w,
                                               const float* __restrict__ b,
                                               float* __restrict__ out) {
    int og = blockIdx.y;
    int sp = blockIdx.x * 256 + threadIdx.x;
    if (sp >= C3H * C3H) return;
    int y = sp / C3H, x = sp - y * C3H;
    int oc0 = og * 4;
    const float* wb = w + oc0 * 180;

    float acc0 = 0.f, acc1 = 0.f, acc2 = 0.f, acc3 = 0.f;
    #pragma unroll
    for (int ic = 0; ic < 20; ++ic) {
        const float* ip = in + ic * C2H * C2S + y * C2S + x;
        float v[3][3];
        #pragma unroll
        for (int ky = 0; ky < 3; ++ky)
            #pragma unroll
            for (int kx = 0; kx < 3; ++kx)
                v[ky][kx] = ip[ky * C2S + kx];
        #pragma unroll
        for (int kk = 0; kk < 9; ++kk) {
            float iv = v[kk / 3][kk % 3];
            acc0 = fmaf(iv, wb[          ic * 9 + kk], acc0);  // uniform
            acc1 = fmaf(iv, wb[180     + ic * 9 + kk], acc1);
            acc2 = fmaf(iv, wb[360     + ic * 9 + kk], acc2);
            acc3 = fmaf(iv, wb[540     + ic * 9 + kk], acc3);
        }
    }
    int o = y * C3S + x;
    out[(oc0 + 0) * C3H * C3S + o] = fmaxf(acc0 + b[oc0 + 0], 0.f);
    out[(oc0 + 1) * C3H * C3S + o] = fmaxf(acc1 + b[oc0 + 1], 0.f);
    out[(oc0 + 2) * C3H * C3S + o] = fmaxf(acc2 + b[oc0 + 2], 0.f);
    out[(oc0 + 3) * C3H * C3S + o] = fmaxf(acc3 + b[oc0 + 3], 0.f);
}

// ---------------------------------------------------------------------------
// adaptive max 4x4 over [40][C3H][C3S(padded)] -> 640 floats.
// ---------------------------------------------------------------------------
__global__ void amax_k(const float* __restrict__ in, float* __restrict__ out) {
    int ob = blockIdx.x;              // oc*16 + bi*4 + bj
    int oc = ob >> 4, bi = (ob >> 2) & 3, bj = ob & 3;
    int y0 = (bi * C3H) >> 2, y1 = ((bi + 1) * C3H + 3) >> 2;
    int x0 = (bj * C3H) >> 2, x1 = ((bj + 1) * C3H + 3) >> 2;
    int ny = y1 - y0, nx = x1 - x0, tot = ny * nx;
    float m = -1e30f;
    for (int e = threadIdx.x; e < tot; e += 64) {
        int yy = e / nx, xx = e - yy * nx;
        m = fmaxf(m, in[oc * C3H * C3S + (y0 + yy) * C3S + x0 + xx]);
    }
    #pragma unroll
    for (int o = 32; o > 0; o >>= 1) m = fmaxf(m, __shfl_down(m, o, 64));
    if (threadIdx.x == 0) out[ob] = m;
}

// ---------------------------------------------------------------------------
// fc1 (640->64) + relu + fc2 (64->10). 256 threads: 4 lanes per fc1 row.
// ---------------------------------------------------------------------------
__global__ void fc_k(const float* __restrict__ h, const float* __restrict__ w1,
                     const float* __restrict__ b1, const float* __restrict__ w2,
                     const float* __restrict__ b2, float* __restrict__ out) {
    __shared__ float hh[640];
    __shared__ float h1[64];
    int t = threadIdx.x;   // 256
    for (int e = t; e < 640; e += 256) hh[e] = h[e];
    __syncthreads();

    int r = t >> 2, q = t & 3;
    const float4* wr = (const float4*)(w1 + r * 640 + q * 160);
    const float*  hp = hh + q * 160;
    float acc = 0.f;
    #pragma unroll 4
    for (int n = 0; n < 40; ++n) {
        float4 wv = wr[n];
        acc = fmaf(wv.x, hp[n*4+0], acc);
        acc = fmaf(wv.y, hp[n*4+1], acc);
        acc = fmaf(wv.z, hp[n*4+2], acc);
        acc = fmaf(wv.w, hp[n*4+3], acc);
    }
    acc += __shfl_xor(acc, 1, 64);
    acc += __shfl_xor(acc, 2, 64);
    if (q == 0) h1[r] = fmaxf(acc + b1[r], 0.f);
    __syncthreads();

    if (t < 10) {
        float o = b2[t];
        #pragma unroll 8
        for (int n = 0; n < 64; ++n) o = fmaf(h1[n], w2[t * 64 + n], o);
        out[t] = o;
    }
}

// ---------------------------------------------------------------------------
extern "C" void kernel_launch(void* const* d_in, const int* in_sizes, int n_in,
                              void* d_out, int out_size, void* d_ws, size_t ws_size,
                              hipStream_t stream) {
    const float* x   = (const float*)d_in[0];
    const float* qw  = (const float*)d_in[1];
    const float* c2w = (const float*)d_in[2];
    const float* c2b = (const float*)d_in[3];
    const float* c3w = (const float*)d_in[4];
    const float* c3b = (const float*)d_in[5];
    const float* f1w = (const float*)d_in[6];
    const float* f1b = (const float*)d_in[7];
    const float* f2w = (const float*)d_in[8];
    const float* f2b = (const float*)d_in[9];
    float* out = (float*)d_out;

    float*  wsf   = (float*)d_ws;
    float2* M     = (float2*)d_ws;                  // 256 float2 = 2 KB
    float*  qout  = wsf + 512;                      // [4][256][256]
    float*  c2out = qout + 4 * QP * QP;             // [20][125][128]
    float*  c3out = c2out + 20 * C2H * C2S;         // [40][123][128]
    float*  am    = c3out + 40 * C3H * C3S;         // 640

    build_M<<<1, 64, 0, stream>>>(qw, M);
    qconv_pool<<<(QO * QO + 255) / 256, 256, 0, stream>>>(x, M, qout);
    conv2_pool<<<dim3((C2H * C2H + 255) / 256, 20), 256, 0, stream>>>(qout, c2w, c2b, c2out);
    conv3_k<<<dim3((C3H * C3H + 255) / 256, 10), 256, 0, stream>>>(c2out, c3w, c3b, c3out);
    amax_k<<<640, 64, 0, stream>>>(c3out, am);
    fc_k<<<1, 256, 0, stream>>>(am, f1w, f1b, f2w, f2b, out);
}